// Round 10
// baseline (309.937 us; speedup 1.0000x reference)
//
#include <hip/hip_runtime.h>
#include <hip/hip_bf16.h>

#define BDIM 4
#define CDIM 256
#define HDIM 128
#define WDIM 128
#define PP   21
#define DD   10
#define HW   (HDIM*WDIM)

typedef __attribute__((ext_vector_type(8))) short short8;
typedef __attribute__((ext_vector_type(4))) float f32x4;

// stage/read LDS swizzle: spreads both the b64 stage writes (rows step 4)
// and the b128 A-frag reads (rows step 1) across 8 bank slots, <=2-way.
#define SWZ(r) ((((r) & 7) ^ (((r) >> 2) & 7)) << 4)

#define LDS_BUF   24576            // 48 rows x 256c x 2B (one u-window)
#define SOUT_OFF  (2 * LDS_BUF)    // 49152
#define SOUT_P    44               // souts[8y][16x][44 pw-slots] f32
#define LDS_TOTAL (SOUT_OFF + 8 * 16 * SOUT_P * 4)   // 71680

union U8 { short8 s; unsigned u[4]; };

__device__ __forceinline__ unsigned pk2(float f0, float f1) {
    union { __hip_bfloat162 h; unsigned u; } cv;
    cv.h = __float22bfloat162_rn(make_float2(f0, f1));  // lo=f0, hi=f1 (RNE)
    return cv.u;
}

// Fused spatial-correlation: out[b,ph,pw,y,x] = sum_c in1[b,c,y,x]*in2[b,c,u,s],
// u=y+ph-10, s=x+pw-10, zero outside bounds. Loop over u so one staged in2 row
// serves all 8 y's of the block (ph = u-y+10); in1 fragments live in registers.
__global__ __launch_bounds__(256, 2)
void corr_fused_kernel(const float* __restrict__ in1,
                       const float* __restrict__ in2,
                       float* __restrict__ out) {
    extern __shared__ char smem[];
    float* souts = (float*)(smem + SOUT_OFF);
#define SOUT(yy, x, i) souts[(((yy) << 4) + (x)) * SOUT_P + (i)]

    const int tid  = threadIdx.x;
    const int lane = tid & 63;
    const int w    = tid >> 6;     // wave 0..3 -> y pair
    const int col  = lane & 15;
    const int g    = lane >> 4;

    // XCD swizzle: 512 blocks; each XCD owns 2 consecutive y-tiles (all b, xs)
    const int bid = blockIdx.x;
    const int xcd = bid & 7;
    const int i0  = bid >> 3;             // 0..63
    const int xs  = i0 & 7;
    const int b   = (i0 >> 3) & 3;
    const int yt  = xcd * 2 + (i0 >> 5);
    const int y0  = yt * 8;
    const int x0  = xs * 16;

    const int u_lo = (y0 - DD) > 0 ? (y0 - DD) : 0;
    const int u_hi = (y0 + 17) < 127 ? (y0 + 17) : 127;

    const float* in1b = in1 + (size_t)b * CDIM * HW;
    const float* in2b = in2 + (size_t)b * CDIM * HW;

    // ---- in2 prefetch regs: 640 tasks = (cb 0..63 c-quads) x (s4 0..9) ----
    f32x4 fr[3][4];
    auto PRELOAD = [&](int uu) {
        #pragma unroll
        for (int it = 0; it < 3; ++it) {
            const int task = tid + (it << 8);
            const int cb = (task * 6554) >> 16;      // task/10
            const int s4 = task - cb * 10;
            const int s0 = x0 - 12 + s4 * 4;
            const bool act = (task < 640) && (s0 >= 0) && (s0 < WDIM);
            const float* p = in2b + ((size_t)(cb * 4) * HDIM + uu) * WDIM + s0;
            #pragma unroll
            for (int j = 0; j < 4; ++j) {
                f32x4 v = {0.f, 0.f, 0.f, 0.f};
                if (act) v = *(const f32x4*)(p + j * HW);
                fr[it][j] = v;
            }
        }
    };
    // cvt + b64 write into swizzled bf16 [48 rows][256 c] buffer
    auto STAGE_WRITE = [&](char* L) {
        #pragma unroll
        for (int it = 0; it < 3; ++it) {
            const int task = tid + (it << 8);
            if (task < 640) {
                const int cb = (task * 6554) >> 16;
                const int s4 = task - cb * 10;
                #pragma unroll
                for (int j = 0; j < 4; ++j) {
                    const int row = 4 + s4 * 4 + j;
                    uint2 dv;
                    dv.x = pk2(fr[it][0][j], fr[it][1][j]);
                    dv.y = pk2(fr[it][2][j], fr[it][3][j]);
                    const int byte = (row * 512 + cb * 8) ^ SWZ(row);
                    *(uint2*)(L + byte) = dv;
                }
            }
        }
    };

    PRELOAD(u_lo);

    // ---- in1 B-fragments: 2 y's x K=256, fp32 scalar loads + cvt, resident ----
    U8 bfr[2][8];
    #pragma unroll
    for (int yy = 0; yy < 2; ++yy) {
        const int y = y0 + 2 * w + yy;
        #pragma unroll
        for (int k = 0; k < 8; ++k) {
            #pragma unroll
            for (int jw = 0; jw < 4; ++jw) {
                const int c = k * 32 + g * 8 + jw * 2;
                const float f0 = in1b[((size_t)c * HDIM + y) * WDIM + x0 + col];
                const float f1 = in1b[((size_t)(c + 1) * HDIM + y) * WDIM + x0 + col];
                bfr[yy][k].u[jw] = pk2(f0, f1);
            }
        }
    }

    // ---- prologue: zero outputs whose u = y+ph-10 is out of [0,128) ----
    {
        const float4 z = make_float4(0.f, 0.f, 0.f, 0.f);
        for (int yy = 0; yy < 8; ++yy) {
            const int y = y0 + yy;
            int phlo = DD - y;   if (phlo < 0) phlo = 0;
            int phhi = 138 - y;  if (phhi > PP) phhi = PP;
            for (int ph = 0; ph < phlo; ++ph)
                if (tid < 84)
                    *(float4*)(out + (((size_t)(b * PP + ph) * PP + (tid >> 2)) * HDIM + y) * WDIM
                               + x0 + (tid & 3) * 4) = z;
            for (int ph = phhi; ph < PP; ++ph)
                if (tid < 84)
                    *(float4*)(out + (((size_t)(b * PP + ph) * PP + (tid >> 2)) * HDIM + y) * WDIM
                               + x0 + (tid & 3) * 4) = z;
        }
    }

    STAGE_WRITE(smem);           // buf 0 = u_lo
    __syncthreads();
    int cur = 0;

    for (int u = u_lo; u <= u_hi; ++u) {
        if (u < u_hi) PRELOAD(u + 1);    // issue next-row loads early (hide HBM)

        // ---- compute from buf[cur] ----
        const int ph0 = u - (y0 + 2 * w) + DD;    // wave's first y
        const int ph1 = ph0 - 1;                  // second y
        const bool v0 = (unsigned)ph0 < (unsigned)PP;
        const bool v1 = (unsigned)ph1 < (unsigned)PP;
        if (v0 || v1) {
            const char* L = smem + cur * LDS_BUF;
            #pragma unroll
            for (int st = 0; st < 3; ++st) {
                f32x4 a0 = {0.f, 0.f, 0.f, 0.f};
                f32x4 a1 = {0.f, 0.f, 0.f, 0.f};
                const int s_lo = x0 + st * 16 - 16;
                if (s_lo >= 0 && s_lo < WDIM) {       // skip all-zero halo tiles
                    const int srow = st * 16 + col;
                    const int base = srow * 512 + g * 16;
                    const int swz  = SWZ(srow);
                    #pragma unroll
                    for (int k = 0; k < 8; ++k) {
                        const short8 afr = *(const short8*)(L + ((base + k * 64) ^ swz));
                        if (v0) a0 = __builtin_amdgcn_mfma_f32_16x16x32_bf16(afr, bfr[0][k].s, a0, 0, 0, 0);
                        if (v1) a1 = __builtin_amdgcn_mfma_f32_16x16x32_bf16(afr, bfr[1][k].s, a1, 0, 0, 0);
                    }
                }
                // band extract: acc[r] -> pw = pw0 + r; slot = pw + col + 2 (16B-aligned)
                const int pw0 = st * 16 + g * 4 - col - 6;
                if (pw0 >= -3 && pw0 <= 20) {
                    const int slot = pw0 + col + 2;     // = st*16+g*4-4, mult of 4
                    if (v0) *(f32x4*)&SOUT(2 * w,     col, slot) = a0;
                    if (v1) *(f32x4*)&SOUT(2 * w + 1, col, slot) = a1;
                }
            }
        }
        __syncthreads();   // souts complete; buf[cur] reads done

        // ---- store band rows + stage next u into other buffer ----
        #pragma unroll
        for (int it = 0; it < 3; ++it) {
            const int task = tid + (it << 8);
            if (task < 672) {
                const int yy  = (task * 781) >> 16;   // task/84
                const int rem = task - yy * 84;
                const int pw  = rem >> 2;
                const int xq  = rem & 3;
                const int y   = y0 + yy;
                const int ph  = u - y + DD;
                if ((unsigned)ph < (unsigned)PP) {
                    float4 v;
                    v.x = SOUT(yy, xq * 4 + 0, pw + xq * 4 + 0 + 2);
                    v.y = SOUT(yy, xq * 4 + 1, pw + xq * 4 + 1 + 2);
                    v.z = SOUT(yy, xq * 4 + 2, pw + xq * 4 + 2 + 2);
                    v.w = SOUT(yy, xq * 4 + 3, pw + xq * 4 + 3 + 2);
                    *(float4*)(out + (((size_t)(b * PP + ph) * PP + pw) * HDIM + y) * WDIM
                               + x0 + xq * 4) = v;
                }
            }
        }
        if (u < u_hi) STAGE_WRITE(smem + (cur ^ 1) * LDS_BUF);
        __syncthreads();   // next buf staged; souts consumed
        cur ^= 1;
    }
}

extern "C" void kernel_launch(void* const* d_in, const int* in_sizes, int n_in,
                              void* d_out, int out_size, void* d_ws, size_t ws_size,
                              hipStream_t stream) {
    const float* in1 = (const float*)d_in[0];
    const float* in2 = (const float*)d_in[1];
    float* out = (float*)d_out;
    hipFuncSetAttribute((const void*)corr_fused_kernel,
                        hipFuncAttributeMaxDynamicSharedMemorySize, LDS_TOTAL);
    corr_fused_kernel<<<512, 256, LDS_TOTAL, stream>>>(in1, in2, out);
}